// Round 8
// baseline (248.006 us; speedup 1.0000x reference)
//
#include <hip/hip_runtime.h>

// GRUModule: MLP(64->128->128,ELU) -> xg=W_ih proj -> segment-parallel GRU(H=128) -> W_out head
// B=128, T=1024. All GEMMs via mfma_f32_16x16x32_bf16.
// ws: [xg bf16 [b][t][384]: 100,663,296 B][ys bf16 [t*8+g][16][128]: 33,554,432 B] = 128 MiB
// ctrl+segs in d_out[0..540KB); wtab (bf16 frag records, 240KB) at d_out+1MiB.
// R12: split mlp2 + xgproj; h2 staged in ys region. R13: xbuf stride 388.
// R14 FAILED: forced launch_bounds -> VGPR 32 -> spills. R16 FAILED: multi-tile
//      loop -> VGPR 72 -> occupancy 13%. LESSON: scan body affords ZERO extra
//      VGPR; amortization must be register-free.
// R17: scan xg staging via __builtin_amdgcn_global_load_lds (HBM->LDS DMA,
//      zero VGPRs held) into a 3-deep xbuf; counted "s_waitcnt vmcnt(6)" +
//      raw s_barrier per step keeps the NEXT step's loads in flight across
//      the barrier (2 steps of latency coverage vs ~0.5 before). Exactly 6
//      DMA loads/thread/step, unconditional; global stores issued before
//      staging so the newest-6 vmcnt ops are always the staged loads.
//      Single-tile blocks (grid 4160), plain bounds.

#define T_SZ 1024

typedef __attribute__((ext_vector_type(8))) short short8;
typedef __attribute__((ext_vector_type(4))) float f32x4;
typedef unsigned long long u64;
typedef unsigned int uint32;

__device__ __forceinline__ unsigned short f2b(float f){
  return __builtin_bit_cast(unsigned short, (__bf16)f);
}
__device__ __forceinline__ float b2f(unsigned int hs){
  unsigned int u = hs << 16;
  return __builtin_bit_cast(float, u);
}
__device__ __forceinline__ float rcp_f(float x){ return __builtin_amdgcn_rcpf(x); }
__device__ __forceinline__ float elu(float v){ return v > 0.f ? v : __expf(v) - 1.f; }
__device__ __forceinline__ float sigm(float x){ return rcp_f(1.f + __expf(-x)); }
__device__ __forceinline__ float tanh_fast(float x){
  x = fminf(fmaxf(x, -15.f), 15.f);
  float e = __expf(-2.f * x);
  return (1.f - e) * rcp_f(1.f + e);
}
#define MFMA16(a,b,c) __builtin_amdgcn_mfma_f32_16x16x32_bf16(a, b, c, 0, 0, 0)

// ctrl in d_out (uint32*): [1]=n_tiles [2]=slot cursor; segs=C+4096
// wtab records: [0,6144) Whh ((gt*4+ks)*128+n)*4+q | [6144,7168) W1 | [7168,9216) W2
//               [9216,15360) Wih

// ---------------------------------------------------------------------------
// wprep: all weights fp32 -> bf16 frag-swizzled uint4 records.
// ---------------------------------------------------------------------------
__global__ __launch_bounds__(512) void wprep(
    const float* __restrict__ Whh, const float* __restrict__ W1,
    const float* __restrict__ W2,  const float* __restrict__ Wih,
    uint4* __restrict__ wtab)
{
  int rec = blockIdx.x*512 + threadIdx.x;
  if(rec >= 15360) return;
  const float* p;
  if(rec < 6144){
    int q = rec & 3, n_ = (rec >> 2) & 127, ks = (rec >> 9) & 3, gt = rec >> 11;
    p = Whh + (size_t)(n_ + 128*gt)*128 + ks*32 + q*8;
  } else if(rec < 7168){
    int r = rec - 6144;
    int q = r & 3, n_ = (r >> 2) & 127, ks = r >> 9;
    p = W1 + (size_t)n_*64 + ks*32 + q*8;
  } else if(rec < 9216){
    int r = rec - 7168;
    int q = r & 3, n_ = (r >> 2) & 127, ks = r >> 9;
    p = W2 + (size_t)n_*128 + ks*32 + q*8;
  } else {
    int r = rec - 9216;
    int q = r & 3, n_ = (r >> 2) & 127, ks = (r >> 9) & 3, gt = r >> 11;
    p = Wih + (size_t)(n_ + 128*gt)*128 + ks*32 + q*8;
  }
  uint4 o;
  o.x = (uint32)f2b(p[0]) | ((uint32)f2b(p[1]) << 16);
  o.y = (uint32)f2b(p[2]) | ((uint32)f2b(p[3]) << 16);
  o.z = (uint32)f2b(p[4]) | ((uint32)f2b(p[5]) << 16);
  o.w = (uint32)f2b(p[6]) | ((uint32)f2b(p[7]) << 16);
  wtab[rec] = o;
}

// ---------------------------------------------------------------------------
// seg_build: unchanged.
// ---------------------------------------------------------------------------
__global__ __launch_bounds__(512) void seg_build(const int* __restrict__ ii, uint32* C){
  __shared__ uint32 lh[1024];
  __shared__ uint32 lbase[1024];
  __shared__ uint32 ssum[512];
  __shared__ uint32 sbase;
  uint32* segs = C + 4096;
  const int tid = threadIdx.x;
  const int wv = tid >> 6, lane = tid & 63;
  const int b = blockIdx.x*8 + wv;

  for(int i = tid; i < 1024; i += 512) lh[i] = 0u;
  __syncthreads();

  u64 bal[16], mb[16];
  #pragma unroll
  for(int c=0;c<16;c++){
    int t = c*64 + lane;
    int m = ii[b*T_SZ + t];
    mb[c]  = __ballot(m != 0);
    bal[c] = __ballot((m != 0) || (t == 0));
  }
  int fsA[16]; int nx = T_SZ;
  #pragma unroll
  for(int c=15;c>=0;c--){ fsA[c]=nx; if(bal[c]) nx = c*64 + __builtin_ctzll(bal[c]); }

  int lenA[16], tA[16], rkA[16];
  #pragma unroll
  for(int c=0;c<16;c++){
    lenA[c] = 0;
    if((bal[c] >> lane) & 1ull){
      int t = c*64 + lane;
      u64 hi = (lane < 63) ? (bal[c] >> (lane+1)) : 0ull;
      int nxt = hi ? (t + 1 + __builtin_ctzll(hi)) : fsA[c];
      int len = nxt - t;
      int rst = (int)((mb[c] >> lane) & 1ull);
      len -= rst; t += rst;
      if(len > 0){
        lenA[c] = len; tA[c] = t;
        rkA[c] = (int)atomicAdd(&lh[1024 - len], 1u);
      }
    }
  }
  __syncthreads();

  uint32 c0 = lh[2*tid], c1 = lh[2*tid+1];
  ssum[tid] = c0 + c1;
  __syncthreads();
  #pragma unroll
  for(int off=1; off<512; off<<=1){
    uint32 v = (tid >= off) ? ssum[tid-off] : 0u;
    __syncthreads();
    ssum[tid] += v;
    __syncthreads();
  }
  uint32 excl = tid ? ssum[tid-1] : 0u;
  lbase[2*tid]   = excl;
  lbase[2*tid+1] = excl + c0;
  uint32 total = ssum[511];
  uint32 padded = (total + 15u) & ~15u;
  if(tid == 0){
    sbase = atomicAdd(&C[2], padded);
    atomicAdd(&C[1], padded >> 4);
  }
  __syncthreads();
  const uint32 base = sbase;

  #pragma unroll
  for(int c=0;c<16;c++){
    if(lenA[c] > 0){
      uint32 slot = base + lbase[1024 - lenA[c]] + (uint32)rkA[c];
      segs[slot] = ((uint32)b << 21) | ((uint32)tA[c] << 11) | (uint32)lenA[c];
    }
  }
  for(uint32 i = total + tid; i < padded; i += 512) segs[base + i] = 0u;
}

// ---------------------------------------------------------------------------
// K1a mlp2: x -> h1(LDS) -> h2 (global, ys-layout). Unchanged from R16.
// ---------------------------------------------------------------------------
__global__ __launch_bounds__(512) void mlp2(
    const float* __restrict__ x,
    const uint4* __restrict__ wtab,
    const float* __restrict__ b1, const float* __restrict__ b2,
    unsigned short* __restrict__ h2)
{
  __shared__ __align__(16) char smem[35840];
  unsigned short* xs  = (unsigned short*)smem;            // [4][16][72]
  unsigned short* h1l = (unsigned short*)(smem + 18432);  // [4][16][136]
  const int tid = threadIdx.x;
  const int wv = tid >> 6, l = tid & 63, quad = l >> 4, col = l & 15;
  const int n = 16*wv + col;

  short8 w1f[2], w2f[4];
  #pragma unroll
  for(int ks=0; ks<2; ks++)
    w1f[ks] = __builtin_bit_cast(short8, wtab[6144 + (ks*128 + n)*4 + quad]);
  #pragma unroll
  for(int ks=0; ks<4; ks++)
    w2f[ks] = __builtin_bit_cast(short8, wtab[7168 + (ks*128 + n)*4 + quad]);
  const float b1v = b1[n], b2v = b2[n];

  const int srow = tid >> 5, sk = tid & 31;

  for(int tile = blockIdx.x; tile < 2048; tile += gridDim.x){
    const int g = tile & 7, t0 = (tile >> 3) * 4;
    {
      const float* src = x + (size_t)(16*g + srow)*(T_SZ*64) + (size_t)t0*64;
      #pragma unroll
      for(int j=0; j<2; j++){
        int s = sk + 32*j;
        float4 v = ((const float4*)src)[s];
        int tt = s >> 4, k = (s & 15) * 4;
        unsigned short* dst = xs + (tt*16 + srow)*72 + k;
        dst[0]=f2b(v.x); dst[1]=f2b(v.y); dst[2]=f2b(v.z); dst[3]=f2b(v.w);
      }
    }
    __syncthreads();                                   // (1) xs ready
    #pragma unroll
    for(int tt=0; tt<4; tt++){
      f32x4 acc = {b1v, b1v, b1v, b1v};
      #pragma unroll
      for(int ks=0; ks<2; ks++){
        short8 a = *(const short8*)&xs[(tt*16 + col)*72 + ks*32 + quad*8];
        acc = MFMA16(a, w1f[ks], acc);
      }
      #pragma unroll
      for(int r=0; r<4; r++)
        h1l[(tt*16 + quad*4 + r)*136 + n] = f2b(elu(acc[r]));
    }
    __syncthreads();                                   // (2) h1l ready
    #pragma unroll
    for(int tt=0; tt<4; tt++){
      f32x4 acc = {b2v, b2v, b2v, b2v};
      #pragma unroll
      for(int ks=0; ks<4; ks++){
        short8 a = *(const short8*)&h1l[(tt*16 + col)*136 + ks*32 + quad*8];
        acc = MFMA16(a, w2f[ks], acc);
      }
      const int t = t0 + tt;
      #pragma unroll
      for(int r=0; r<4; r++){
        int row = quad*4 + r;
        h2[((size_t)(t*8 + g)*16 + row)*128 + n] = f2b(elu(acc[r]));
      }
    }
    __syncthreads();                                   // xs/h1l reusable
  }
}

// ---------------------------------------------------------------------------
// K1b xgproj: h2(ys region) -> xg + reset-step gates (overwrites ys rows in
// place) + hT. Predicated xg stores. Unchanged from R16.
// ---------------------------------------------------------------------------
__global__ __launch_bounds__(512) void xgproj(
    const unsigned short* h2, const int* __restrict__ ii,
    const uint4* __restrict__ wtab,
    const float* __restrict__ bih, const float* __restrict__ bhh,
    unsigned short* __restrict__ xg, unsigned short* ys,
    float* __restrict__ hT)
{
  __shared__ __align__(16) unsigned short h2l[4*16*136];
  __shared__ int iil[64];
  const int tid = threadIdx.x;
  const int wv = tid >> 6, l = tid & 63, quad = l >> 4, col = l & 15;
  const int n = 16*wv + col;

  short8 wif[3][4];
  #pragma unroll
  for(int gt=0; gt<3; gt++){
    #pragma unroll
    for(int ks=0; ks<4; ks++)
      wif[gt][ks] = __builtin_bit_cast(short8, wtab[9216 + ((gt*4 + ks)*128 + n)*4 + quad]);
  }
  float bihv[3], bhhv[3];
  #pragma unroll
  for(int gt=0; gt<3; gt++){ bihv[gt] = bih[n + 128*gt]; bhhv[gt] = bhh[n + 128*gt]; }

  for(int tile = blockIdx.x; tile < 2048; tile += gridDim.x){
    const int g = tile & 7, t0 = (tile >> 3) * 4;
    {
      const int w = tid >> 3, j = tid & 7;
      const int tt = w >> 4, row = w & 15;
      const unsigned short* src = h2 + ((size_t)((t0 + tt)*8 + g)*16 + row)*128 + j*16;
      unsigned short* dst = &h2l[(tt*16 + row)*136 + j*16];
      #pragma unroll
      for(int i2=0; i2<4; i2++)
        *(u64*)(dst + i2*4) = *(const u64*)(src + i2*4);
    }
    if(tid < 64) iil[tid] = ii[(16*g + (tid & 15))*T_SZ + t0 + (tid >> 4)];
    __syncthreads();                                   // h2 tile resident

    uint32 xgo[4];
    #pragma unroll
    for(int r=0; r<4; r++)
      xgo[r] = (((uint32)(16*g + quad*4 + r) << 10) + (uint32)t0) * 384u + (uint32)n;
    #pragma unroll
    for(int tt=0; tt<4; tt++){
      f32x4 a0 = {bihv[0], bihv[0], bihv[0], bihv[0]};
      f32x4 a1 = {bihv[1], bihv[1], bihv[1], bihv[1]};
      f32x4 a2 = {bihv[2], bihv[2], bihv[2], bihv[2]};
      #pragma unroll
      for(int ks=0; ks<4; ks++){
        short8 a = *(const short8*)&h2l[(tt*16 + col)*136 + ks*32 + quad*8];
        a0 = MFMA16(a, wif[0][ks], a0);
        a1 = MFMA16(a, wif[1][ks], a1);
        a2 = MFMA16(a, wif[2][ks], a2);
      }
      const int t = t0 + tt;
      #pragma unroll
      for(int r=0; r<4; r++){
        int row = quad*4 + r;
        if(iil[tt*16 + row] != 0){
          float rr = sigm(a0[r] + bhhv[0]);
          float zz = sigm(a1[r] + bhhv[1]);
          float nn = tanh_fast(a2[r] + rr*bhhv[2]);
          float h1 = (1.f - zz)*nn;
          ys[((size_t)(t*8 + g)*16 + row)*128 + n] = f2b(h1);   // in-place over h2 row
          if(t == T_SZ-1)
            hT[(16*g + row)*128 + n] = h1;
        } else {
          unsigned short* p = xg + xgo[r] + (uint32)(tt*384);
          p[0]   = f2b(a0[r]);
          p[128] = f2b(a1[r]);
          p[256] = f2b(a2[r]);
        }
      }
    }
    __syncthreads();                                   // protect h2l/iil reuse
  }
}

// ---------------------------------------------------------------------------
// K2 R17: segment-parallel GRU scan, single tile per block (grid 4160, early
// exit). xg staged via global_load_lds DMA into 3-deep xbuf; counted
// vmcnt(6) + raw s_barrier per step -> next step's loads stay in flight
// across the barrier. Zero VGPRs held for staging.
// LDS: hl 2x4352 + xbuf 3x12544 + seg arrays ~= 46.5 KB.
// ---------------------------------------------------------------------------
__global__ __launch_bounds__(512) void gru_seg_scan(
    const unsigned short* __restrict__ xg,
    const float* __restrict__ hx,
    const uint4* __restrict__ wbf, const float* __restrict__ bhh,
    const uint32* __restrict__ C,
    unsigned short* __restrict__ ys, float* __restrict__ hT)
{
  __shared__ unsigned short hl[2][16*136];                  // 8704 B
  __shared__ __align__(16) unsigned short xbuf[3][16*392];  // 37632 B
  __shared__ int srb[16], srt[16], srlen[16];
  const uint32 ntile = C[1];
  const uint32 tile = blockIdx.x;
  if(tile >= ntile) return;

  const int tid = threadIdx.x;
  const int wv = tid >> 6, l = tid & 63, quad = l >> 4, col = l & 15;
  const int nidx = 16*wv + col;
  const int frow = tid >> 5, fk = tid & 31;
  const uint32* segs = C + 4096;

  short8 whf[3][4];
  float bhv[3];
  #pragma unroll
  for(int gt=0; gt<3; gt++){
    bhv[gt] = bhh[nidx + 128*gt];
    #pragma unroll
    for(int ks=0; ks<4; ks++){
      uint4 w = wbf[((gt*4 + ks)*128 + nidx)*4 + quad];
      whf[gt][ks] = __builtin_bit_cast(short8, w);
    }
  }

  if(tid < 16){
    uint32 w = segs[16*tile + (uint32)tid];
    srb[tid] = (int)(w >> 21);
    srt[tid] = (int)((w >> 11) & 1023u);
    srlen[tid] = (int)(w & 2047u);
  }
  __syncthreads();
  const int maxlen = srlen[0];
  const int fb = srb[frow], ft = srt[frow], fl = srlen[frow];

  // Stage one step-row set (16 rows x 768B) via global_load_lds DMA.
  // Wave wv covers global chunks gc=wv*6+c (c<6); row r=gc/3, part=gc%3.
  // LDS dest (wave-uniform): xbuf[buf] + r*784 + part*256 (+ lane*4 by HW).
  // Exactly 6 vmcnt ops per thread per call, unconditional (clamped t).
  auto stage = [&](int buf, int tstep){
    #pragma unroll
    for(int c=0; c<6; c++){
      int gc = wv*6 + c;
      int r  = gc / 3, part = gc - r*3;
      int sl = srlen[r];
      int tc = (tstep < sl) ? tstep : (sl > 0 ? sl - 1 : 0);
      const unsigned short* src = xg
          + ((size_t)(srb[r]*T_SZ + srt[r] + tc))*384 + part*128 + l*2;
      char* dst = (char*)&xbuf[buf][0] + r*784 + part*256;
      __builtin_amdgcn_global_load_lds(
          (const __attribute__((address_space(1))) void*)src,
          (__attribute__((address_space(3))) void*)dst, 4, 0, 0);
    }
  };

  // cooperative h0 fill into hl[0]
  if(fl > 0){
    if(ft == 0){
      float4 hv = *(const float4*)(hx + fb*128 + fk*4);
      unsigned short* d = &hl[0][frow*136 + fk*4];
      d[0]=f2b(hv.x); d[1]=f2b(hv.y); d[2]=f2b(hv.z); d[3]=f2b(hv.w);
    } else {
      u64 hv = *(const u64*)(ys + ((size_t)((ft-1)*8 + (fb>>4))*16 + (fb&15))*128 + fk*4);
      *(u64*)&hl[0][frow*136 + fk*4] = hv;
    }
  } else {
    *(u64*)&hl[0][frow*136 + fk*4] = 0ull;
  }
  stage(0, 0);
  stage(1, 1);
  __syncthreads();                 // full drain: xbuf[0],xbuf[1],hl[0] ready

  float hreg[4];
  #pragma unroll
  for(int r=0; r<4; r++){
    int row = quad*4 + r;
    hreg[r] = (srlen[row] > 0 && srt[row] == 0)
                ? hx[srb[row]*128 + nidx]
                : b2f(hl[0][row*136 + nidx]);
  }

  int cur = 0;     // hl parity
  int xc  = 0;     // xbuf holding step i
  int xs3 = 2;     // xbuf to stage step i+2
  for(int i=0; i<maxlen; i++){
    if(i >= 1){
      // wait for step-i's staged set (older) while step-i+1's 6 stay in flight
      asm volatile("s_waitcnt vmcnt(6) lgkmcnt(0)" ::: "memory");
      __builtin_amdgcn_s_barrier();
      __builtin_amdgcn_sched_barrier(0);
    }
    // delayed ys/hT store of step i-1 (global stores BEFORE staging so the
    // newest-6 vmcnt ops at the next wait are exactly the staged loads)
    if(i >= 1 && i <= fl){
      int t = ft + i - 1;
      u64 hv = *(const u64*)&hl[cur][frow*136 + fk*4];
      *(u64*)(ys + ((size_t)(t*8 + (fb>>4))*16 + (fb&15))*128 + fk*4) = hv;
      if(i == fl && ft + fl == T_SZ){
        #pragma unroll
        for(int j=0; j<4; j++)
          hT[fb*128 + fk*4 + j] = b2f(hl[cur][frow*136 + fk*4 + j]);
      }
    }
    stage(xs3, i + 2);
    // MFMA: hg = Whh @ h_i
    short8 af[4];
    #pragma unroll
    for(int ks=0; ks<4; ks++)
      af[ks] = *(const short8*)&hl[cur][col*136 + ks*32 + quad*8];
    f32x4 ar = {bhv[0], bhv[0], bhv[0], bhv[0]};
    f32x4 az = {bhv[1], bhv[1], bhv[1], bhv[1]};
    f32x4 an = {bhv[2], bhv[2], bhv[2], bhv[2]};
    #pragma unroll
    for(int ks=0; ks<4; ks++){
      ar = MFMA16(af[ks], whf[0][ks], ar);
      az = MFMA16(af[ks], whf[1][ks], az);
      an = MFMA16(af[ks], whf[2][ks], an);
    }
    // gates (xbuf stride 392 shorts)
    const unsigned short* xb = &xbuf[xc][0];
    #pragma unroll
    for(int r=0; r<4; r++){
      int row = quad*4 + r;
      float xrv = b2f(xb[row*392 +       nidx]);
      float xzv = b2f(xb[row*392 + 128 + nidx]);
      float xnv = b2f(xb[row*392 + 256 + nidx]);
      float rr = sigm(xrv + ar[r]);
      float zz = sigm(xzv + az[r]);
      float nn = tanh_fast(xnv + rr*an[r]);
      float hnew = (1.f - zz)*nn + zz*hreg[r];
      hreg[r] = hnew;
      hl[cur^1][row*136 + nidx] = f2b(hnew);
    }
    cur ^= 1;
    xc  = (xc  == 2) ? 0 : xc  + 1;
    xs3 = (xs3 == 2) ? 0 : xs3 + 1;
  }
  // flush final step
  __syncthreads();
  if(maxlen >= 1 && fl == maxlen){
    int t = ft + maxlen - 1;
    u64 hv = *(const u64*)&hl[cur][frow*136 + fk*4];
    *(u64*)(ys + ((size_t)(t*8 + (fb>>4))*16 + (fb&15))*128 + fk*4) = hv;
    if(ft + fl == T_SZ){
      #pragma unroll
      for(int j=0; j<4; j++)
        hT[fb*128 + fk*4 + j] = b2f(hl[cur][frow*136 + fk*4 + j]);
    }
  }
}

// ---------------------------------------------------------------------------
// K3: out = y @ W_out.T + b_out. (unchanged)
// ---------------------------------------------------------------------------
__global__ __launch_bounds__(256) void out_gemm(
    const unsigned short* __restrict__ ys,
    const float* __restrict__ Wout, const float* __restrict__ bout,
    float* __restrict__ outp)
{
  const int tid = threadIdx.x;
  const int wv = tid >> 6, l = tid & 63, quad = l >> 4, col = l & 15;
  const int n = 16*wv + col;
  short8 wof[4];
  #pragma unroll
  for(int ks=0; ks<4; ks++){
    const float* p = Wout + n*128 + ks*32 + quad*8;
    const float4* q = (const float4*)p;
    float4 u0 = q[0], u1 = q[1];
    short8 v;
    v[0]=(short)f2b(u0.x); v[1]=(short)f2b(u0.y); v[2]=(short)f2b(u0.z); v[3]=(short)f2b(u0.w);
    v[4]=(short)f2b(u1.x); v[5]=(short)f2b(u1.y); v[6]=(short)f2b(u1.z); v[7]=(short)f2b(u1.w);
    wof[ks] = v;
  }
  const float bov = bout[n];
  for(int tile = blockIdx.x; tile < 8192; tile += gridDim.x){
    const int t = tile >> 3, g = tile & 7;
    const unsigned short* yt = ys + (size_t)tile * 16 * 128;
    f32x4 acc = {bov, bov, bov, bov};
    #pragma unroll
    for(int ks=0; ks<4; ks++){
      short8 a = *(const short8*)&yt[col*128 + ks*32 + quad*8];
      acc = MFMA16(a, wof[ks], acc);
    }
    #pragma unroll
    for(int r=0; r<4; r++)
      outp[(size_t)(16*g + quad*4 + r)*(T_SZ*64) + (size_t)t*64 + n] = acc[r];
  }
}

extern "C" void kernel_launch(void* const* d_in, const int* in_sizes, int n_in,
                              void* d_out, int out_size, void* d_ws, size_t ws_size,
                              hipStream_t stream)
{
  const float* x    = (const float*)d_in[0];
  const int*   ii   = (const int*)  d_in[1];
  const float* hx   = (const float*)d_in[2];
  const float* W1   = (const float*)d_in[3];
  const float* b1   = (const float*)d_in[4];
  const float* W2   = (const float*)d_in[5];
  const float* b2   = (const float*)d_in[6];
  const float* Wih  = (const float*)d_in[7];
  const float* bih  = (const float*)d_in[8];
  const float* Whh  = (const float*)d_in[9];
  const float* bhh  = (const float*)d_in[10];
  const float* Wout = (const float*)d_in[11];
  const float* bout = (const float*)d_in[12];

  float* outp = (float*)d_out;
  float* hT   = outp + (size_t)128 * T_SZ * 64;
  uint32* C   = (uint32*)d_out;
  uint4* wtab = (uint4*)((char*)d_out + (1u<<20));   // 240KB at +1MiB, dead until out_gemm

  unsigned short* xg = (unsigned short*)d_ws;                          // 100,663,296 B
  unsigned short* ys = (unsigned short*)((char*)d_ws + 100663296ull);  //  33,554,432 B (h2 then ys)

  hipMemsetAsync(C, 0, 64, stream);
  wprep      <<<dim3(30),   dim3(512),  0, stream>>>(Whh, W1, W2, Wih, wtab);
  seg_build  <<<dim3(16),   dim3(512),  0, stream>>>(ii, C);
  mlp2       <<<dim3(1024), dim3(512),  0, stream>>>(x, wtab, b1, b2, ys);
  xgproj     <<<dim3(1024), dim3(512),  0, stream>>>(ys, ii, wtab, bih, bhh, xg, ys, hT);
  gru_seg_scan<<<dim3(4160),dim3(512),  0, stream>>>(xg, hx, wtab, bhh, C, ys, hT);
  out_gemm   <<<dim3(2048), dim3(256),  0, stream>>>(ys, Wout, bout, outp);
}

// Round 9
// 217.714 us; speedup vs baseline: 1.1391x; 1.1391x over previous
//
#include <hip/hip_runtime.h>

// GRUModule: MLP(64->128->128,ELU) -> xg=W_ih proj -> segment-parallel GRU(H=128) -> W_out head
// B=128, T=1024. All GEMMs via mfma_f32_16x16x32_bf16.
// ws: [xg bf16 [b][t][384]: 100,663,296 B][ys bf16 [t*8+g][16][128]: 33,554,432 B] = 128 MiB
// ctrl+segs in d_out[0..540KB); wtab (bf16 frag records, 240KB) at d_out+1MiB.
// R12: split mlp2 + xgproj; h2 staged in ys region.
// R14/R16/R17 all FAILED the same way: any mechanism added to the scan body
//   (forced bounds / multi-tile loop / DMA staging) crosses the 64-VGPR
//   boundary -> occupancy collapse. HARD RULE: scan = R15 body, untouched.
// R18: (a) scan: exact R15 body (47us, VGPR 64) + s_setprio(1/0) around the
//      MFMA cluster only (zero-VGPR scheduler hint).
//      (b) xgproj: register-staged double-buffered h2 tiles, ONE barrier per
//      tile, grid 512 (4 tiles/block) -- staging regs cost ~8 VGPR, fine here.
//      (c) wprep+seg_build fused into one `prep` kernel (one less launch gap).

#define T_SZ 1024

typedef __attribute__((ext_vector_type(8))) short short8;
typedef __attribute__((ext_vector_type(4))) float f32x4;
typedef unsigned long long u64;
typedef unsigned int uint32;

__device__ __forceinline__ unsigned short f2b(float f){
  return __builtin_bit_cast(unsigned short, (__bf16)f);
}
__device__ __forceinline__ float b2f(unsigned int hs){
  unsigned int u = hs << 16;
  return __builtin_bit_cast(float, u);
}
__device__ __forceinline__ float rcp_f(float x){ return __builtin_amdgcn_rcpf(x); }
__device__ __forceinline__ float elu(float v){ return v > 0.f ? v : __expf(v) - 1.f; }
__device__ __forceinline__ float sigm(float x){ return rcp_f(1.f + __expf(-x)); }
__device__ __forceinline__ float tanh_fast(float x){
  x = fminf(fmaxf(x, -15.f), 15.f);
  float e = __expf(-2.f * x);
  return (1.f - e) * rcp_f(1.f + e);
}
#define MFMA16(a,b,c) __builtin_amdgcn_mfma_f32_16x16x32_bf16(a, b, c, 0, 0, 0)

// ctrl in d_out (uint32*): [1]=n_tiles [2]=slot cursor; segs=C+4096
// wtab records: [0,6144) Whh ((gt*4+ks)*128+n)*4+q | [6144,7168) W1 | [7168,9216) W2
//               [9216,15360) Wih

// ---------------------------------------------------------------------------
// prep: fused wprep (blocks 0..29) + seg_build (blocks 30..45).
// ---------------------------------------------------------------------------
__global__ __launch_bounds__(512) void prep(
    const float* __restrict__ Whh, const float* __restrict__ W1,
    const float* __restrict__ W2,  const float* __restrict__ Wih,
    uint4* __restrict__ wtab, const int* __restrict__ ii, uint32* C)
{
  if(blockIdx.x < 30){
    // ---- wprep ----
    int rec = blockIdx.x*512 + threadIdx.x;
    if(rec >= 15360) return;
    const float* p;
    if(rec < 6144){
      int q = rec & 3, n_ = (rec >> 2) & 127, ks = (rec >> 9) & 3, gt = rec >> 11;
      p = Whh + (size_t)(n_ + 128*gt)*128 + ks*32 + q*8;
    } else if(rec < 7168){
      int r = rec - 6144;
      int q = r & 3, n_ = (r >> 2) & 127, ks = r >> 9;
      p = W1 + (size_t)n_*64 + ks*32 + q*8;
    } else if(rec < 9216){
      int r = rec - 7168;
      int q = r & 3, n_ = (r >> 2) & 127, ks = r >> 9;
      p = W2 + (size_t)n_*128 + ks*32 + q*8;
    } else {
      int r = rec - 9216;
      int q = r & 3, n_ = (r >> 2) & 127, ks = (r >> 9) & 3, gt = r >> 11;
      p = Wih + (size_t)(n_ + 128*gt)*128 + ks*32 + q*8;
    }
    uint4 o;
    o.x = (uint32)f2b(p[0]) | ((uint32)f2b(p[1]) << 16);
    o.y = (uint32)f2b(p[2]) | ((uint32)f2b(p[3]) << 16);
    o.z = (uint32)f2b(p[4]) | ((uint32)f2b(p[5]) << 16);
    o.w = (uint32)f2b(p[6]) | ((uint32)f2b(p[7]) << 16);
    wtab[rec] = o;
  } else {
    // ---- seg_build ----
    __shared__ uint32 lh[1024];
    __shared__ uint32 lbase[1024];
    __shared__ uint32 ssum[512];
    __shared__ uint32 sbase;
    uint32* segs = C + 4096;
    const int tid = threadIdx.x;
    const int wv = tid >> 6, lane = tid & 63;
    const int b = (blockIdx.x - 30)*8 + wv;

    for(int i = tid; i < 1024; i += 512) lh[i] = 0u;
    __syncthreads();

    u64 bal[16], mb[16];
    #pragma unroll
    for(int c=0;c<16;c++){
      int t = c*64 + lane;
      int m = ii[b*T_SZ + t];
      mb[c]  = __ballot(m != 0);
      bal[c] = __ballot((m != 0) || (t == 0));
    }
    int fsA[16]; int nx = T_SZ;
    #pragma unroll
    for(int c=15;c>=0;c--){ fsA[c]=nx; if(bal[c]) nx = c*64 + __builtin_ctzll(bal[c]); }

    int lenA[16], tA[16], rkA[16];
    #pragma unroll
    for(int c=0;c<16;c++){
      lenA[c] = 0;
      if((bal[c] >> lane) & 1ull){
        int t = c*64 + lane;
        u64 hi = (lane < 63) ? (bal[c] >> (lane+1)) : 0ull;
        int nxt = hi ? (t + 1 + __builtin_ctzll(hi)) : fsA[c];
        int len = nxt - t;
        int rst = (int)((mb[c] >> lane) & 1ull);
        len -= rst; t += rst;
        if(len > 0){
          lenA[c] = len; tA[c] = t;
          rkA[c] = (int)atomicAdd(&lh[1024 - len], 1u);
        }
      }
    }
    __syncthreads();

    uint32 c0 = lh[2*tid], c1 = lh[2*tid+1];
    ssum[tid] = c0 + c1;
    __syncthreads();
    #pragma unroll
    for(int off=1; off<512; off<<=1){
      uint32 v = (tid >= off) ? ssum[tid-off] : 0u;
      __syncthreads();
      ssum[tid] += v;
      __syncthreads();
    }
    uint32 excl = tid ? ssum[tid-1] : 0u;
    lbase[2*tid]   = excl;
    lbase[2*tid+1] = excl + c0;
    uint32 total = ssum[511];
    uint32 padded = (total + 15u) & ~15u;
    if(tid == 0){
      sbase = atomicAdd(&C[2], padded);
      atomicAdd(&C[1], padded >> 4);
    }
    __syncthreads();
    const uint32 base = sbase;

    #pragma unroll
    for(int c=0;c<16;c++){
      if(lenA[c] > 0){
        uint32 slot = base + lbase[1024 - lenA[c]] + (uint32)rkA[c];
        segs[slot] = ((uint32)b << 21) | ((uint32)tA[c] << 11) | (uint32)lenA[c];
      }
    }
    for(uint32 i = total + tid; i < padded; i += 512) segs[base + i] = 0u;
  }
}

// ---------------------------------------------------------------------------
// K1a mlp2: x -> h1(LDS) -> h2 (global, ys-layout). Grid 1024, 2 tiles/block.
// ---------------------------------------------------------------------------
__global__ __launch_bounds__(512) void mlp2(
    const float* __restrict__ x,
    const uint4* __restrict__ wtab,
    const float* __restrict__ b1, const float* __restrict__ b2,
    unsigned short* __restrict__ h2)
{
  __shared__ __align__(16) char smem[35840];
  unsigned short* xs  = (unsigned short*)smem;            // [4][16][72]
  unsigned short* h1l = (unsigned short*)(smem + 18432);  // [4][16][136]
  const int tid = threadIdx.x;
  const int wv = tid >> 6, l = tid & 63, quad = l >> 4, col = l & 15;
  const int n = 16*wv + col;

  short8 w1f[2], w2f[4];
  #pragma unroll
  for(int ks=0; ks<2; ks++)
    w1f[ks] = __builtin_bit_cast(short8, wtab[6144 + (ks*128 + n)*4 + quad]);
  #pragma unroll
  for(int ks=0; ks<4; ks++)
    w2f[ks] = __builtin_bit_cast(short8, wtab[7168 + (ks*128 + n)*4 + quad]);
  const float b1v = b1[n], b2v = b2[n];

  const int srow = tid >> 5, sk = tid & 31;

  for(int tile = blockIdx.x; tile < 2048; tile += gridDim.x){
    const int g = tile & 7, t0 = (tile >> 3) * 4;
    {
      const float* src = x + (size_t)(16*g + srow)*(T_SZ*64) + (size_t)t0*64;
      #pragma unroll
      for(int j=0; j<2; j++){
        int s = sk + 32*j;
        float4 v = ((const float4*)src)[s];
        int tt = s >> 4, k = (s & 15) * 4;
        unsigned short* dst = xs + (tt*16 + srow)*72 + k;
        dst[0]=f2b(v.x); dst[1]=f2b(v.y); dst[2]=f2b(v.z); dst[3]=f2b(v.w);
      }
    }
    __syncthreads();                                   // (1) xs ready
    #pragma unroll
    for(int tt=0; tt<4; tt++){
      f32x4 acc = {b1v, b1v, b1v, b1v};
      #pragma unroll
      for(int ks=0; ks<2; ks++){
        short8 a = *(const short8*)&xs[(tt*16 + col)*72 + ks*32 + quad*8];
        acc = MFMA16(a, w1f[ks], acc);
      }
      #pragma unroll
      for(int r=0; r<4; r++)
        h1l[(tt*16 + quad*4 + r)*136 + n] = f2b(elu(acc[r]));
    }
    __syncthreads();                                   // (2) h1l ready
    #pragma unroll
    for(int tt=0; tt<4; tt++){
      f32x4 acc = {b2v, b2v, b2v, b2v};
      #pragma unroll
      for(int ks=0; ks<4; ks++){
        short8 a = *(const short8*)&h1l[(tt*16 + col)*136 + ks*32 + quad*8];
        acc = MFMA16(a, w2f[ks], acc);
      }
      const int t = t0 + tt;
      #pragma unroll
      for(int r=0; r<4; r++){
        int row = quad*4 + r;
        h2[((size_t)(t*8 + g)*16 + row)*128 + n] = f2b(elu(acc[r]));
      }
    }
    __syncthreads();                                   // xs/h1l reusable
  }
}

// ---------------------------------------------------------------------------
// K1b xgproj R18: register-staged double-buffered h2 tiles, ONE barrier per
// tile. Grid 512 (4 tiles/block). Per iteration: issue next-tile loads to
// regs -> compute current from h2l[p] -> write regs to h2l[p^1] -> barrier.
// In-place ys overwrite safe: tile rows are block-private.
// LDS: 2x17408 + 2x256 = 35.3 KB.
// ---------------------------------------------------------------------------
__global__ __launch_bounds__(512) void xgproj(
    const unsigned short* h2, const int* __restrict__ ii,
    const uint4* __restrict__ wtab,
    const float* __restrict__ bih, const float* __restrict__ bhh,
    unsigned short* __restrict__ xg, unsigned short* ys,
    float* __restrict__ hT)
{
  __shared__ __align__(16) unsigned short h2l[2][4*16*136];
  __shared__ int iil[2][64];
  const int tid = threadIdx.x;
  const int wv = tid >> 6, l = tid & 63, quad = l >> 4, col = l & 15;
  const int n = 16*wv + col;

  short8 wif[3][4];
  #pragma unroll
  for(int gt=0; gt<3; gt++){
    #pragma unroll
    for(int ks=0; ks<4; ks++)
      wif[gt][ks] = __builtin_bit_cast(short8, wtab[9216 + ((gt*4 + ks)*128 + n)*4 + quad]);
  }
  float bihv[3], bhhv[3];
  #pragma unroll
  for(int gt=0; gt<3; gt++){ bihv[gt] = bih[n + 128*gt]; bhhv[gt] = bhh[n + 128*gt]; }

  // staging roles
  const int w = tid >> 3, j = tid & 7;       // row-slot 0..63, 16B chunk 0..7
  const int stt = w >> 4, srow2 = w & 15;

  // prologue: stage tile blockIdx.x into buf 0
  int tile = blockIdx.x;
  {
    const int g = tile & 7, t0 = (tile >> 3) * 4;
    const unsigned short* src = h2 + ((size_t)((t0 + stt)*8 + g)*16 + srow2)*128 + j*16;
    unsigned short* dst = &h2l[0][(stt*16 + srow2)*136 + j*16];
    #pragma unroll
    for(int i2=0; i2<4; i2++)
      *(u64*)(dst + i2*4) = *(const u64*)(src + i2*4);
    if(tid < 64) iil[0][tid] = ii[(16*g + (tid & 15))*T_SZ + t0 + (tid >> 4)];
  }
  __syncthreads();

  int p = 0;
  while(tile < 2048){
    const int ntile = tile + (int)gridDim.x;
    // issue next-tile loads (latency hidden under compute)
    u64 r0=0, r1=0, r2=0, r3=0; int iv = 0;
    if(ntile < 2048){
      const int g = ntile & 7, t0 = (ntile >> 3) * 4;
      const unsigned short* src = h2 + ((size_t)((t0 + stt)*8 + g)*16 + srow2)*128 + j*16;
      r0 = ((const u64*)src)[0]; r1 = ((const u64*)src)[1];
      r2 = ((const u64*)src)[2]; r3 = ((const u64*)src)[3];
      if(tid < 64) iv = ii[(16*g + (tid & 15))*T_SZ + t0 + (tid >> 4)];
    }
    // compute current tile from h2l[p]
    {
      const int g = tile & 7, t0 = (tile >> 3) * 4;
      uint32 xgo[4];
      #pragma unroll
      for(int r=0; r<4; r++)
        xgo[r] = (((uint32)(16*g + quad*4 + r) << 10) + (uint32)t0) * 384u + (uint32)n;
      #pragma unroll
      for(int tt=0; tt<4; tt++){
        f32x4 a0 = {bihv[0], bihv[0], bihv[0], bihv[0]};
        f32x4 a1 = {bihv[1], bihv[1], bihv[1], bihv[1]};
        f32x4 a2 = {bihv[2], bihv[2], bihv[2], bihv[2]};
        #pragma unroll
        for(int ks=0; ks<4; ks++){
          short8 a = *(const short8*)&h2l[p][(tt*16 + col)*136 + ks*32 + quad*8];
          a0 = MFMA16(a, wif[0][ks], a0);
          a1 = MFMA16(a, wif[1][ks], a1);
          a2 = MFMA16(a, wif[2][ks], a2);
        }
        const int t = t0 + tt;
        #pragma unroll
        for(int r=0; r<4; r++){
          int row = quad*4 + r;
          if(iil[p][tt*16 + row] != 0){
            float rr = sigm(a0[r] + bhhv[0]);
            float zz = sigm(a1[r] + bhhv[1]);
            float nn = tanh_fast(a2[r] + rr*bhhv[2]);
            float h1 = (1.f - zz)*nn;
            ys[((size_t)(t*8 + g)*16 + row)*128 + n] = f2b(h1);   // in-place over h2 row
            if(t == T_SZ-1)
              hT[(16*g + row)*128 + n] = h1;
          } else {
            unsigned short* pp = xg + xgo[r] + (uint32)(tt*384);
            pp[0]   = f2b(a0[r]);
            pp[128] = f2b(a1[r]);
            pp[256] = f2b(a2[r]);
          }
        }
      }
    }
    // commit staged regs to the other buffer
    if(ntile < 2048){
      unsigned short* dst = &h2l[p^1][(stt*16 + srow2)*136 + j*16];
      *(u64*)(dst     ) = r0; *(u64*)(dst +  4) = r1;
      *(u64*)(dst +  8) = r2; *(u64*)(dst + 12) = r3;
      if(tid < 64) iil[p^1][tid] = iv;
    }
    __syncthreads();                                   // single barrier/tile
    tile = ntile; p ^= 1;
  }
}

// ---------------------------------------------------------------------------
// K2 R18: segment-parallel GRU scan == exact R15 body (47us, VGPR 64) plus
// s_setprio(1/0) around the MFMA cluster (zero-VGPR hint). DO NOT add state.
// ---------------------------------------------------------------------------
__global__ __launch_bounds__(512) void gru_seg_scan(
    const unsigned short* __restrict__ xg,
    const float* __restrict__ hx,
    const uint4* __restrict__ wbf, const float* __restrict__ bhh,
    const uint32* __restrict__ C,
    unsigned short* __restrict__ ys, float* __restrict__ hT)
{
  __shared__ unsigned short hl[2][16*136];       // 2 x 4352 B
  __shared__ unsigned short xbuf[2][16*388];     // 2 x 12416 B
  __shared__ int srb[16], srt[16], srlen[16];
  const uint32 ntile = C[1];
  const uint32 tile = blockIdx.x;
  if(tile >= ntile) return;

  const int tid = threadIdx.x;
  const int wv = tid >> 6, l = tid & 63, quad = l >> 4, col = l & 15;
  const int nidx = 16*wv + col;
  const int frow = tid >> 5, fk = tid & 31;
  const uint32* segs = C + 4096;

  short8 whf[3][4];
  float bhv[3];
  #pragma unroll
  for(int gt=0; gt<3; gt++){
    bhv[gt] = bhh[nidx + 128*gt];
    #pragma unroll
    for(int ks=0; ks<4; ks++){
      uint4 w = wbf[((gt*4 + ks)*128 + nidx)*4 + quad];
      whf[gt][ks] = __builtin_bit_cast(short8, w);
    }
  }

  if(tid < 16){
    uint32 w = segs[16*tile + (uint32)tid];
    srb[tid] = (int)(w >> 21);
    srt[tid] = (int)((w >> 11) & 1023u);
    srlen[tid] = (int)(w & 2047u);
  }
  __syncthreads();
  const int maxlen = srlen[0];
  const int fb = srb[frow], ft = srt[frow], fl = srlen[frow];

  float hreg[4];
  #pragma unroll
  for(int r=0; r<4; r++){
    int row = quad*4 + r;
    int b = srb[row], t0 = srt[row];
    float h0 = 0.f;
    if(srlen[row] > 0){
      h0 = (t0 == 0) ? hx[b*128 + nidx]
                     : b2f(ys[((size_t)((t0-1)*8 + (b>>4))*16 + (b&15))*128 + nidx]);
    }
    hreg[r] = h0;
    hl[0][row*136 + nidx] = f2b(h0);
  }
  // prologue: step-0 xg rows into xbuf[0]
  {
    const unsigned short* src = xg + ((size_t)fb*T_SZ + ft)*384;
    unsigned short* xb = &xbuf[0][frow*388];
    #pragma unroll
    for(int i2=0; i2<3; i2++)
      *(u64*)(xb + i2*128 + fk*4) = *(const u64*)(src + i2*128 + fk*4);
  }

  int cur = 0;
  for(int i=0; i<maxlen; i++){
    __syncthreads();                 // hl[cur]=h_i, xbuf[cur]=xg_i visible
    __builtin_amdgcn_s_setprio(1);
    short8 af[4];
    #pragma unroll
    for(int ks=0; ks<4; ks++)
      af[ks] = *(const short8*)&hl[cur][col*136 + ks*32 + quad*8];
    f32x4 ar = {bhv[0], bhv[0], bhv[0], bhv[0]};
    f32x4 az = {bhv[1], bhv[1], bhv[1], bhv[1]};
    f32x4 an = {bhv[2], bhv[2], bhv[2], bhv[2]};
    #pragma unroll
    for(int ks=0; ks<4; ks++){
      ar = MFMA16(af[ks], whf[0][ks], ar);
      az = MFMA16(af[ks], whf[1][ks], az);
      an = MFMA16(af[ks], whf[2][ks], an);
    }
    __builtin_amdgcn_s_setprio(0);
    // prefetch step i+1 (clamped)
    u64 p0, p1, p2;
    {
      int tc = (i+1 < fl) ? i+1 : (fl > 0 ? fl-1 : 0);
      const unsigned short* src = xg + ((size_t)fb*T_SZ + (ft + tc))*384;
      p0 = *(const u64*)(src +       fk*4);
      p1 = *(const u64*)(src + 128 + fk*4);
      p2 = *(const u64*)(src + 256 + fk*4);
    }
    // cooperative coalesced ys write of step i-1 from hl[cur]
    if(i >= 1 && i <= fl){
      int t = ft + i - 1;
      u64 hv = *(const u64*)&hl[cur][frow*136 + fk*4];
      *(u64*)(ys + ((size_t)(t*8 + (fb>>4))*16 + (fb&15))*128 + fk*4) = hv;
      if(i == fl && ft + fl == T_SZ){
        #pragma unroll
        for(int j=0; j<4; j++)
          hT[fb*128 + fk*4 + j] = b2f(hl[cur][frow*136 + fk*4 + j]);
      }
    }
    // gates
    const unsigned short* xb = &xbuf[cur][0];
    #pragma unroll
    for(int r=0; r<4; r++){
      int row = quad*4 + r;
      float xrv = b2f(xb[row*388 +       nidx]);
      float xzv = b2f(xb[row*388 + 128 + nidx]);
      float xnv = b2f(xb[row*388 + 256 + nidx]);
      float rr = sigm(xrv + ar[r]);
      float zz = sigm(xzv + az[r]);
      float nn = tanh_fast(xnv + rr*an[r]);
      float hnew = (1.f - zz)*nn + zz*hreg[r];
      hreg[r] = hnew;
      hl[cur^1][row*136 + nidx] = f2b(hnew);
    }
    {
      unsigned short* xb2 = &xbuf[cur^1][frow*388];
      *(u64*)(xb2 +       fk*4) = p0;
      *(u64*)(xb2 + 128 + fk*4) = p1;
      *(u64*)(xb2 + 256 + fk*4) = p2;
    }
    cur ^= 1;
  }
  // flush final step
  __syncthreads();
  if(maxlen >= 1 && fl == maxlen){
    int t = ft + maxlen - 1;
    u64 hv = *(const u64*)&hl[cur][frow*136 + fk*4];
    *(u64*)(ys + ((size_t)(t*8 + (fb>>4))*16 + (fb&15))*128 + fk*4) = hv;
    if(ft + fl == T_SZ){
      #pragma unroll
      for(int j=0; j<4; j++)
        hT[fb*128 + fk*4 + j] = b2f(hl[cur][frow*136 + fk*4 + j]);
    }
  }
}

// ---------------------------------------------------------------------------
// K3: out = y @ W_out.T + b_out. (unchanged)
// ---------------------------------------------------------------------------
__global__ __launch_bounds__(256) void out_gemm(
    const unsigned short* __restrict__ ys,
    const float* __restrict__ Wout, const float* __restrict__ bout,
    float* __restrict__ outp)
{
  const int tid = threadIdx.x;
  const int wv = tid >> 6, l = tid & 63, quad = l >> 4, col = l & 15;
  const int n = 16*wv + col;
  short8 wof[4];
  #pragma unroll
  for(int ks=0; ks<4; ks++){
    const float* p = Wout + n*128 + ks*32 + quad*8;
    const float4* q = (const float4*)p;
    float4 u0 = q[0], u1 = q[1];
    short8 v;
    v[0]=(short)f2b(u0.x); v[1]=(short)f2b(u0.y); v[2]=(short)f2b(u0.z); v[3]=(short)f2b(u0.w);
    v[4]=(short)f2b(u1.x); v[5]=(short)f2b(u1.y); v[6]=(short)f2b(u1.z); v[7]=(short)f2b(u1.w);
    wof[ks] = v;
  }
  const float bov = bout[n];
  for(int tile = blockIdx.x; tile < 8192; tile += gridDim.x){
    const int t = tile >> 3, g = tile & 7;
    const unsigned short* yt = ys + (size_t)tile * 16 * 128;
    f32x4 acc = {bov, bov, bov, bov};
    #pragma unroll
    for(int ks=0; ks<4; ks++){
      short8 a = *(const short8*)&yt[col*128 + ks*32 + quad*8];
      acc = MFMA16(a, wof[ks], acc);
    }
    #pragma unroll
    for(int r=0; r<4; r++)
      outp[(size_t)(16*g + quad*4 + r)*(T_SZ*64) + (size_t)t*64 + n] = acc[r];
  }
}

extern "C" void kernel_launch(void* const* d_in, const int* in_sizes, int n_in,
                              void* d_out, int out_size, void* d_ws, size_t ws_size,
                              hipStream_t stream)
{
  const float* x    = (const float*)d_in[0];
  const int*   ii   = (const int*)  d_in[1];
  const float* hx   = (const float*)d_in[2];
  const float* W1   = (const float*)d_in[3];
  const float* b1   = (const float*)d_in[4];
  const float* W2   = (const float*)d_in[5];
  const float* b2   = (const float*)d_in[6];
  const float* Wih  = (const float*)d_in[7];
  const float* bih  = (const float*)d_in[8];
  const float* Whh  = (const float*)d_in[9];
  const float* bhh  = (const float*)d_in[10];
  const float* Wout = (const float*)d_in[11];
  const float* bout = (const float*)d_in[12];

  float* outp = (float*)d_out;
  float* hT   = outp + (size_t)128 * T_SZ * 64;
  uint32* C   = (uint32*)d_out;
  uint4* wtab = (uint4*)((char*)d_out + (1u<<20));   // 240KB at +1MiB, dead until out_gemm

  unsigned short* xg = (unsigned short*)d_ws;                          // 100,663,296 B
  unsigned short* ys = (unsigned short*)((char*)d_ws + 100663296ull);  //  33,554,432 B (h2 then ys)

  hipMemsetAsync(C, 0, 64, stream);
  prep       <<<dim3(46),   dim3(512),  0, stream>>>(Whh, W1, W2, Wih, wtab, ii, C);
  mlp2       <<<dim3(1024), dim3(512),  0, stream>>>(x, wtab, b1, b2, ys);
  xgproj     <<<dim3(512),  dim3(512),  0, stream>>>(ys, ii, wtab, bih, bhh, xg, ys, hT);
  gru_seg_scan<<<dim3(4160),dim3(512),  0, stream>>>(xg, hx, wtab, bhh, C, ys, hT);
  out_gemm   <<<dim3(2048), dim3(256),  0, stream>>>(ys, Wout, bout, outp);
}